// Round 7
// baseline (340.782 us; speedup 1.0000x reference)
//
#include <hip/hip_runtime.h>
#include <hip/hip_bf16.h>

// RPN head: conv3x3(512->512)+ReLU, then 1x1 cls(18)+2-way softmax and 1x1 bbox(36).
// conv = bf16 MFMA implicit GEMM, 256x256 tile, 8 waves (2Mx4N), BK=64.
// KEY CHANGE (R7): A (weights) is GATHERED FROM GLOBAL into registers (L1-served,
// 16-line/instr perfect gather) -- only B is LDS-staged (dbuf 64KB). This takes the
// A read traffic off the DS pipe, which the R4-R6 arithmetic showed was the binding
// resource (DS ~3072 cyc/K-tile > MFMA 2061 cyc; observed 4733 = serialized sum).

typedef __bf16 bf16_t;
typedef __attribute__((ext_vector_type(8))) __bf16 bf16x8;
typedef __attribute__((ext_vector_type(4))) __bf16 bf16x4;
typedef __attribute__((ext_vector_type(4))) float f32x4;

#define HW 3800
#define NPOS (8 * HW)
#define XP_IMG (52 * 78 * 512)

__device__ __forceinline__ void gload_lds16(const bf16_t* g, char* l) {
  __builtin_amdgcn_global_load_lds(
      (const __attribute__((address_space(1))) unsigned int*)g,
      (__attribute__((address_space(3))) unsigned int*)l, 16, 0, 0);
}

// base_feat [8][512][50][76] f32 -> Xp [8][52][78][512] bf16.
__global__ __launch_bounds__(256) void pad_nhwc(const float* __restrict__ x,
                                                bf16_t* __restrict__ Xp) {
  const int t = threadIdx.x;
  const int blk = blockIdx.x;
  if (blk < 1600) {
    __shared__ __align__(16) bf16_t tile[76][136];  // [w][c], 272B rows
    const int cb = blk & 3;
    int r = blk >> 2;
    const int h = r % 50, b = r / 50;
#pragma unroll
    for (int it = 0; it < 10; ++it) {
      int idx = it * 256 + t;
      if (idx < 2432) {
        int c = idx / 19, w4 = idx - c * 19;
        const float4 v = *(const float4*)(x +
            (((size_t)(b * 512 + cb * 128 + c)) * 50 + h) * 76 + w4 * 4);
        tile[w4 * 4 + 0][c] = (bf16_t)v.x;
        tile[w4 * 4 + 1][c] = (bf16_t)v.y;
        tile[w4 * 4 + 2][c] = (bf16_t)v.z;
        tile[w4 * 4 + 3][c] = (bf16_t)v.w;
      }
    }
    __syncthreads();
#pragma unroll
    for (int it = 0; it < 5; ++it) {
      int idx = it * 256 + t;
      if (idx < 1216) {
        int w = idx >> 4, c8 = idx & 15;
        bf16x8 v = *(const bf16x8*)&tile[w][c8 * 8];
        *(bf16x8*)(Xp + ((size_t)(b * 52 + h + 1) * 78 + (w + 1)) * 512 +
                   cb * 128 + c8 * 8) = v;
      }
    }
  } else {
    const int blk2 = blk - 1600;            // 16 halo blocks
    const int b = blk2 >> 1, half = blk2 & 1;
    bf16x8 z;
#pragma unroll
    for (int j = 0; j < 8; ++j) z[j] = (bf16_t)0.f;
#pragma unroll
    for (int it = 0; it < 32; ++it) {
      int idx = it * 256 + t;
      int q = half * 128 + (idx >> 6);
      int c8 = idx & 63;
      int h, w;
      if (q < 78)       { h = 0;           w = q; }
      else if (q < 156) { h = 51;          w = q - 78; }
      else if (q < 206) { h = q - 156 + 1; w = 0; }
      else              { h = q - 206 + 1; w = 77; }
      *(bf16x8*)(Xp + ((size_t)(b * 52 + h) * 78 + w) * 512 + c8 * 8) = z;
    }
  }
}

// conv_w [512][512][3][3] f32 -> Wt [9][co][ci] bf16.
__global__ __launch_bounds__(256) void wtrans(const float* __restrict__ cw,
                                              bf16_t* __restrict__ Wt) {
  __shared__ bf16_t lw[4608];
  const int t = threadIdx.x;
  const int co = blockIdx.x;
  const float* src = cw + (size_t)co * 4608;
#pragma unroll
  for (int it = 0; it < 18; ++it) {
    int idx = it * 256 + t;
    lw[idx] = (bf16_t)src[idx];
  }
  __syncthreads();
#pragma unroll
  for (int s = 0; s < 9; ++s) {
    int ci = t * 2;
    bf16_t v0 = lw[ci * 9 + s], v1 = lw[(ci + 1) * 9 + s];
    bf16_t* dst = Wt + ((size_t)s * 512 + co) * 512 + ci;
    dst[0] = v0; dst[1] = v1;
  }
}

// cls_w [18][512], bbox_w [36][512] f32 -> Whb [64][512] bf16, rows permuted.
__global__ __launch_bounds__(256) void whb_build(const float* __restrict__ clsw,
                                                 const float* __restrict__ boxw,
                                                 bf16_t* __restrict__ Whb) {
  int t = blockIdx.x * 256 + threadIdx.x;   // 64*512 = 32768
  int ci = t & 511; int row = t >> 9;
  float v = 0.f;
  if (row < 18) {
    int a = row >> 1, logit = row & 1;
    v = clsw[(logit * 9 + a) * 512 + ci];
  } else if (row < 54) {
    v = boxw[(row - 18) * 512 + ci];
  }
  Whb[(size_t)row * 512 + ci] = (bf16_t)v;
}

// implicit-GEMM conv3x3: 256co x 256pos, BK=64, 8 waves (2Mx4N).
// A gathered global->regs (triple-rotated halves); B dbuf-staged in 64KB LDS.
__global__ __launch_bounds__(512, 2) void conv3x3(const bf16_t* __restrict__ Xp,
                                                  const bf16_t* __restrict__ Wt,
                                                  const float* __restrict__ convb,
                                                  bf16_t* __restrict__ rc2) {
  __shared__ __align__(16) char smem[65536];   // B dbuf: buf q at q*32768
  const int tid = threadIdx.x;
  const int lane = tid & 63;
  const int wv = tid >> 6;          // 0..7
  const int wm = wv >> 2;           // 0..1  (co half)
  const int wn = wv & 3;            // 0..3  (pos quarter)
  const int lm = lane & 15, lg = lane >> 4;

  // XCD swizzle: 240 blocks, 240%8==0 -> one image per XCD
  const int raw = blockIdx.x;
  const int wg = (raw & 7) * 30 + (raw >> 3);
  const int b = wg / 30;
  const int rem = wg - b * 30;
  const int co_base = (rem & 1) * 256;
  const int pos_base = (rem >> 1) * 256;
  const bf16_t* XpB = Xp + (size_t)b * XP_IMG;

  // B staging descriptors (proven R4 path): d = i*512+tid, row r=d>>3,
  // chunk swizzle c = p ^ (r&7) applied on the SOURCE; LDS dest linear.
  int hB[4], wB[4], cB[4];
#pragma unroll
  for (int i = 0; i < 4; ++i) {
    int d = i * 512 + tid;
    int r = d >> 3, c = (d & 7) ^ (r & 7);
    int m = pos_base + r; if (m > HW - 1) m = HW - 1;   // tail clamp
    hB[i] = m / 76; wB[i] = m - (m / 76) * 76; cB[i] = c * 8;
  }

  // B fragment read offsets (XOR chunk swizzle; 2-way per quarter-group = free)
  int bOff[4][2];
#pragma unroll
  for (int n = 0; n < 4; ++n)
#pragma unroll
    for (int ks = 0; ks < 2; ++ks)
      bOff[n][ks] = (wn * 64 + n * 16 + lm) * 128 + (((ks * 4 + lg) ^ (lm & 7)) << 4);

  // A gather base: per-lane row co_base + wm*128 + half*64 + m*16 + lm, 16B at
  // byte offset (cb*64 + ks*32 + lg*8)*2. Quarter-group = 16 distinct 64B lines.
  const bf16_t* aBase = Wt + (size_t)(co_base + wm * 128 + lm) * 512 + lg * 8;

  f32x4 acc[8][4];
#pragma unroll
  for (int i = 0; i < 8; ++i)
#pragma unroll
    for (int j = 0; j < 4; ++j) acc[i][j] = (f32x4){0.f, 0.f, 0.f, 0.f};

#define STAGE_B(KT, BASE) {                                                     \
    const int s_ = (KT) >> 3, cb_ = (KT) & 7;                                   \
    const int kh_ = s_ / 3, kw_ = s_ - kh_ * 3;                                 \
    _Pragma("unroll")                                                           \
    for (int i_ = 0; i_ < 4; ++i_)                                              \
      gload_lds16(XpB + (size_t)((hB[i_] + kh_) * 78 + (wB[i_] + kw_)) * 512 +  \
                      cB[i_] + cb_ * 64,                                        \
                  (BASE) + (i_ * 512 + tid) * 16);                              \
  }
// LOAD_A: 8 x global_load_dwordx4 into DST (bf16x8[8]), half HF (rows HF*64+m*16)
#define LOAD_A(KT, DST, HF) {                                                   \
    const int s_ = (KT) >> 3, cb_ = (KT) & 7;                                   \
    const bf16_t* p_ = aBase + (size_t)s_ * 262144 + (size_t)(HF) * 64 * 512 +  \
                       cb_ * 64;                                                \
    _Pragma("unroll")                                                           \
    for (int m_ = 0; m_ < 4; ++m_)                                              \
      _Pragma("unroll")                                                         \
      for (int ks_ = 0; ks_ < 2; ++ks_)                                         \
        DST[m_ * 2 + ks_] = *(const bf16x8*)(p_ + m_ * 16 * 512 + ks_ * 32);    \
  }

  bf16x8 a0[8], a1[8], bfr[4][2];

  // prologue: stage B(0); gather A(0) both halves; wait B only (A via auto-waits)
  STAGE_B(0, smem);
  LOAD_A(0, a0, 0);
  LOAD_A(0, a1, 1);
  asm volatile("s_waitcnt vmcnt(16)" ::: "memory");   // 16 A-loads still in flight
  __builtin_amdgcn_s_barrier();
  __builtin_amdgcn_sched_barrier(0);

  for (int t = 0; t < 72; ++t) {
    const char* base = smem + (t & 1) * 32768;
    char* nxt = smem + ((t + 1) & 1) * 32768;
    const bool more = (t < 71);

    if (more) STAGE_B(t + 1, nxt);                    // 4 gload_lds, drains at boundary

    // B fragments for this tile (8 ds_read_b128)
#pragma unroll
    for (int n = 0; n < 4; ++n)
#pragma unroll
      for (int ks = 0; ks < 2; ++ks)
        bfr[n][ks] = *(const bf16x8*)(base + bOff[n][ks]);

    // half0: rows wm*128 + 0..63 (compiler inserts counted vmcnt for a0)
    __builtin_amdgcn_s_setprio(1);
#pragma unroll
    for (int m = 0; m < 4; ++m)
#pragma unroll
      for (int n = 0; n < 4; ++n)
#pragma unroll
        for (int ks = 0; ks < 2; ++ks)
          acc[m][n] = __builtin_amdgcn_mfma_f32_16x16x32_bf16(
              a0[m * 2 + ks], bfr[n][ks], acc[m][n], 0, 0, 0);
    __builtin_amdgcn_s_setprio(0);
    if (more) LOAD_A(t + 1, a0, 0);                   // refill a0 for next tile

    // half1: rows wm*128 + 64..127
    __builtin_amdgcn_s_setprio(1);
#pragma unroll
    for (int m = 0; m < 4; ++m)
#pragma unroll
      for (int n = 0; n < 4; ++n)
#pragma unroll
        for (int ks = 0; ks < 2; ++ks)
          acc[4 + m][n] = __builtin_amdgcn_mfma_f32_16x16x32_bf16(
              a1[m * 2 + ks], bfr[n][ks], acc[4 + m][n], 0, 0, 0);
    __builtin_amdgcn_s_setprio(0);
    if (more) LOAD_A(t + 1, a1, 1);                   // refill a1

    if (t == 71) break;
    // boundary: B-stage(t+1) is the oldest of 20 outstanding VMEM ops ->
    // vmcnt(16) drains exactly the 4 staging loads; 16 A-loads stay in flight.
    __builtin_amdgcn_sched_barrier(0);
    asm volatile("s_waitcnt vmcnt(16)" ::: "memory");
    __builtin_amdgcn_s_barrier();
    __builtin_amdgcn_sched_barrier(0);
  }
#undef STAGE_B
#undef LOAD_A

  // epilogue: bias + ReLU, store NHWC rc2[(b*HW+pos)][co], 8B per fragment
  const size_t outRow = (size_t)b * HW;
#pragma unroll
  for (int m = 0; m < 8; ++m) {
    const int co = co_base + wm * 128 + m * 16 + lg * 4;
    const float4 bias = *(const float4*)(convb + co);
#pragma unroll
    for (int n = 0; n < 4; ++n) {
      const int pos = pos_base + wn * 64 + n * 16 + lm;
      if (pos < HW) {
        bf16x4 v;
        float z0 = acc[m][n][0] + bias.x; v[0] = (bf16_t)(z0 > 0.f ? z0 : 0.f);
        float z1 = acc[m][n][1] + bias.y; v[1] = (bf16_t)(z1 > 0.f ? z1 : 0.f);
        float z2 = acc[m][n][2] + bias.z; v[2] = (bf16_t)(z2 > 0.f ? z2 : 0.f);
        float z3 = acc[m][n][3] + bias.w; v[3] = (bf16_t)(z3 > 0.f ? z3 : 0.f);
        *(bf16x4*)(rc2 + (outRow + pos) * 512 + co) = v;
      }
    }
  }
}

// heads: C[64co][128pos] = Whb[64][512] x rc2[pos][512], fused bias/softmax/store.
__global__ __launch_bounds__(256) void heads_mfma(const bf16_t* __restrict__ rc2,
                                                  const bf16_t* __restrict__ Whb,
                                                  const float* __restrict__ clsb,
                                                  const float* __restrict__ boxb,
                                                  float* __restrict__ out) {
  __shared__ __align__(16) char smem[24576];  // A:[0,8K) B:[8K,24K)
  const int t = threadIdx.x, lane = t & 63, wv = t >> 6;
  const int lm = lane & 15, lg = lane >> 4, lx = lane & 7;
  const int pos_base = blockIdx.x * 128;

  int aSrc[2], bSrc[4];
#pragma unroll
  for (int i = 0; i < 2; ++i) {
    int d = i * 256 + t;
    int r = d >> 3, p = d & 7, c = p ^ (r & 7);
    aSrc[i] = r * 512 + c * 8;
  }
#pragma unroll
  for (int i = 0; i < 4; ++i) {
    int d = i * 256 + t;
    int r = d >> 3, p = d & 7, c = p ^ (r & 7);
    int pg = pos_base + r; if (pg > NPOS - 1) pg = NPOS - 1;
    bSrc[i] = pg * 512 + c * 8;
  }

  f32x4 acc[4][2];
#pragma unroll
  for (int i = 0; i < 4; ++i)
#pragma unroll
    for (int j = 0; j < 2; ++j) acc[i][j] = (f32x4){0.f, 0.f, 0.f, 0.f};

  for (int cb = 0; cb < 8; ++cb) {
    __syncthreads();
#pragma unroll
    for (int i = 0; i < 2; ++i) {
      int d = i * 256 + t;
      gload_lds16(Whb + aSrc[i] + cb * 64, &smem[d * 16]);
    }
#pragma unroll
    for (int i = 0; i < 4; ++i) {
      int d = i * 256 + t;
      gload_lds16(rc2 + (size_t)bSrc[i] + cb * 64, &smem[8192 + d * 16]);
    }
    __syncthreads();
#pragma unroll
    for (int ks = 0; ks < 2; ++ks) {
      const int koff = ((ks * 4 + lg) ^ lx) << 4;
      bf16x8 af[4], bfr[2];
#pragma unroll
      for (int f = 0; f < 4; ++f)
        af[f] = *(const bf16x8*)&smem[(f * 16 + lm) * 128 + koff];
#pragma unroll
      for (int f = 0; f < 2; ++f)
        bfr[f] = *(const bf16x8*)&smem[8192 + (wv * 32 + f * 16 + lm) * 128 + koff];
#pragma unroll
      for (int fa = 0; fa < 4; ++fa)
#pragma unroll
        for (int fb = 0; fb < 2; ++fb)
          acc[fa][fb] = __builtin_amdgcn_mfma_f32_16x16x32_bf16(
              af[fa], bfr[fb], acc[fa][fb], 0, 0, 0);
    }
  }

  float* boxOut = out + (size_t)8 * 18 * HW;
#pragma unroll
  for (int fb = 0; fb < 2; ++fb) {
    const int pg = pos_base + wv * 32 + fb * 16 + lm;
    if (pg < NPOS) {
      const int b = pg / HW;
      const int m = pg - b * HW;
#pragma unroll
      for (int fa = 0; fa < 4; ++fa) {
        const int base = fa * 16 + lg * 4;
#pragma unroll
        for (int pr = 0; pr < 2; ++pr) {
          const int row0 = base + pr * 2;
          const float v0 = acc[fa][fb][pr * 2];
          const float v1 = acc[fa][fb][pr * 2 + 1];
          if (row0 < 18) {
            const int a = row0 >> 1;
            const float s0 = v0 + clsb[a];
            const float s1 = v1 + clsb[9 + a];
            const float mx = fmaxf(s0, s1);
            const float e0 = expf(s0 - mx), e1 = expf(s1 - mx);
            const float inv = 1.0f / (e0 + e1);
            out[((size_t)(b * 18 + a)) * HW + m] = e0 * inv;
            out[((size_t)(b * 18 + 9 + a)) * HW + m] = e1 * inv;
          } else if (row0 < 54) {
            const int c0 = row0 - 18;
            boxOut[((size_t)(b * 36 + c0)) * HW + m] = v0 + boxb[c0];
            boxOut[((size_t)(b * 36 + c0 + 1)) * HW + m] = v1 + boxb[c0 + 1];
          }
        }
      }
    }
  }
}

extern "C" void kernel_launch(void* const* d_in, const int* in_sizes, int n_in,
                              void* d_out, int out_size, void* d_ws, size_t ws_size,
                              hipStream_t stream) {
  (void)in_sizes; (void)n_in; (void)out_size; (void)ws_size;
  const float* base_feat = (const float*)d_in[0];
  const float* conv_w = (const float*)d_in[4];
  const float* conv_b = (const float*)d_in[5];
  const float* cls_w  = (const float*)d_in[6];
  const float* cls_b  = (const float*)d_in[7];
  const float* bbox_w = (const float*)d_in[8];
  const float* bbox_b = (const float*)d_in[9];

  char* ws = (char*)d_ws;
  bf16_t* Xp  = (bf16_t*)(ws);                 // 8*52*78*512*2   = 33,226,752 B
  bf16_t* Wt  = (bf16_t*)(ws + 33226752);      // 9*512*512*2     =  4,718,592 B
  bf16_t* rc2 = (bf16_t*)(ws + 37945344);      // 30400*512*2     = 31,129,600 B (NHWC)
  bf16_t* Whb = (bf16_t*)(ws + 69074944);      // 64*512*2        =     65,536 B

  hipLaunchKernelGGL(pad_nhwc,   dim3(1616), dim3(256), 0, stream, base_feat, Xp);
  hipLaunchKernelGGL(wtrans,     dim3(512),  dim3(256), 0, stream, conv_w, Wt);
  hipLaunchKernelGGL(whb_build,  dim3(128),  dim3(256), 0, stream, cls_w, bbox_w, Whb);
  hipLaunchKernelGGL(conv3x3,    dim3(240),  dim3(512), 0, stream, Xp, Wt, conv_b, rc2);
  hipLaunchKernelGGL(heads_mfma, dim3(238),  dim3(256), 0, stream, rc2, Whb, cls_b, bbox_b,
                     (float*)d_out);
}

// Round 8
// 160.466 us; speedup vs baseline: 2.1237x; 2.1237x over previous
//
#include <hip/hip_runtime.h>
#include <hip/hip_bf16.h>

// RPN head: conv3x3(512->512)+ReLU, then 1x1 cls(18)+2-way softmax and 1x1 bbox(36).
// conv = bf16 MFMA implicit GEMM, 256x256 tile, 8 waves (2Mx4N), BK=64, dbuf 128KB,
// m201-faithful 8-phase schedule: per phase {reads; 1 half-tile stage; barrier;
// lgkmcnt(0); setprio MFMA x16; barrier}, vmcnt(6) only at phases 4 and 8.

typedef __bf16 bf16_t;
typedef __attribute__((ext_vector_type(8))) __bf16 bf16x8;
typedef __attribute__((ext_vector_type(4))) __bf16 bf16x4;
typedef __attribute__((ext_vector_type(4))) float f32x4;

#define HW 3800
#define NPOS (8 * HW)
#define XP_IMG (52 * 78 * 512)

__device__ __forceinline__ void gload_lds16(const bf16_t* g, char* l) {
  __builtin_amdgcn_global_load_lds(
      (const __attribute__((address_space(1))) unsigned int*)g,
      (__attribute__((address_space(3))) unsigned int*)l, 16, 0, 0);
}

// base_feat [8][512][50][76] f32 -> Xp [8][52][78][512] bf16.
__global__ __launch_bounds__(256) void pad_nhwc(const float* __restrict__ x,
                                                bf16_t* __restrict__ Xp) {
  const int t = threadIdx.x;
  const int blk = blockIdx.x;
  if (blk < 1600) {
    __shared__ __align__(16) bf16_t tile[76][136];  // [w][c], 272B rows
    const int cb = blk & 3;
    int r = blk >> 2;
    const int h = r % 50, b = r / 50;
#pragma unroll
    for (int it = 0; it < 10; ++it) {
      int idx = it * 256 + t;
      if (idx < 2432) {
        int c = idx / 19, w4 = idx - c * 19;
        const float4 v = *(const float4*)(x +
            (((size_t)(b * 512 + cb * 128 + c)) * 50 + h) * 76 + w4 * 4);
        tile[w4 * 4 + 0][c] = (bf16_t)v.x;
        tile[w4 * 4 + 1][c] = (bf16_t)v.y;
        tile[w4 * 4 + 2][c] = (bf16_t)v.z;
        tile[w4 * 4 + 3][c] = (bf16_t)v.w;
      }
    }
    __syncthreads();
#pragma unroll
    for (int it = 0; it < 5; ++it) {
      int idx = it * 256 + t;
      if (idx < 1216) {
        int w = idx >> 4, c8 = idx & 15;
        bf16x8 v = *(const bf16x8*)&tile[w][c8 * 8];
        *(bf16x8*)(Xp + ((size_t)(b * 52 + h + 1) * 78 + (w + 1)) * 512 +
                   cb * 128 + c8 * 8) = v;
      }
    }
  } else {
    const int blk2 = blk - 1600;            // 16 halo blocks
    const int b = blk2 >> 1, half = blk2 & 1;
    bf16x8 z;
#pragma unroll
    for (int j = 0; j < 8; ++j) z[j] = (bf16_t)0.f;
#pragma unroll
    for (int it = 0; it < 32; ++it) {
      int idx = it * 256 + t;
      int q = half * 128 + (idx >> 6);
      int c8 = idx & 63;
      int h, w;
      if (q < 78)       { h = 0;           w = q; }
      else if (q < 156) { h = 51;          w = q - 78; }
      else if (q < 206) { h = q - 156 + 1; w = 0; }
      else              { h = q - 206 + 1; w = 77; }
      *(bf16x8*)(Xp + ((size_t)(b * 52 + h) * 78 + w) * 512 + c8 * 8) = z;
    }
  }
}

// conv_w [512][512][3][3] f32 -> Wt [9][co][ci] bf16.
__global__ __launch_bounds__(256) void wtrans(const float* __restrict__ cw,
                                              bf16_t* __restrict__ Wt) {
  __shared__ bf16_t lw[4608];
  const int t = threadIdx.x;
  const int co = blockIdx.x;
  const float* src = cw + (size_t)co * 4608;
#pragma unroll
  for (int it = 0; it < 18; ++it) {
    int idx = it * 256 + t;
    lw[idx] = (bf16_t)src[idx];
  }
  __syncthreads();
#pragma unroll
  for (int s = 0; s < 9; ++s) {
    int ci = t * 2;
    bf16_t v0 = lw[ci * 9 + s], v1 = lw[(ci + 1) * 9 + s];
    bf16_t* dst = Wt + ((size_t)s * 512 + co) * 512 + ci;
    dst[0] = v0; dst[1] = v1;
  }
}

// cls_w [18][512], bbox_w [36][512] f32 -> Whb [64][512] bf16, rows permuted.
__global__ __launch_bounds__(256) void whb_build(const float* __restrict__ clsw,
                                                 const float* __restrict__ boxw,
                                                 bf16_t* __restrict__ Whb) {
  int t = blockIdx.x * 256 + threadIdx.x;   // 64*512 = 32768
  int ci = t & 511; int row = t >> 9;
  float v = 0.f;
  if (row < 18) {
    int a = row >> 1, logit = row & 1;
    v = clsw[(logit * 9 + a) * 512 + ci];
  } else if (row < 54) {
    v = boxw[(row - 18) * 512 + ci];
  }
  Whb[(size_t)row * 512 + ci] = (bf16_t)v;
}

// implicit-GEMM conv3x3: 256co x 256pos, BK=64, 8 waves (2Mx4N), dbuf 128KB,
// m201 8-phase schedule over 72 K-tiles (36 iterations x 2 tiles).
__global__ __launch_bounds__(512, 2) void conv3x3(const bf16_t* __restrict__ Xp,
                                                  const bf16_t* __restrict__ Wt,
                                                  const float* __restrict__ convb,
                                                  bf16_t* __restrict__ rc2) {
  // buffer q at q*65536: A rows 0..255 at [row*128], B at [32768 + row*128]
  __shared__ __align__(16) char smem[131072];
  const int tid = threadIdx.x;
  const int lane = tid & 63;
  const int wv = tid >> 6;          // 0..7
  const int wm = wv >> 2;           // 0..1  (co half)
  const int wn = wv & 3;            // 0..3  (pos quarter)
  const int lm = lane & 15, lg = lane >> 4;

  // XCD swizzle: 240 blocks, 240%8==0 -> one image per XCD
  const int raw = blockIdx.x;
  const int wg = (raw & 7) * 30 + (raw >> 3);
  const int b = wg / 30;
  const int rem = wg - b * 30;
  const int co_base = (rem & 1) * 256;
  const int pos_base = (rem >> 1) * 256;
  const bf16_t* XpB = Xp + (size_t)b * XP_IMG;

  // ---- staging descriptors ----
  // A half mh: striped rows {0..63, 128..191} (mh=0 == fragment rows a0-3 of both
  // wm groups) / {64..127, 192..255} (mh=1 == a4-7). 2 loads/thread each.
  int aSrc[2][2], aDst[2][2];
#pragma unroll
  for (int mh = 0; mh < 2; ++mh)
#pragma unroll
    for (int i = 0; i < 2; ++i) {
      int d = i * 512 + tid;
      int rl = d >> 3, p = d & 7;
      int rp = ((rl >> 6) << 7) + mh * 64 + (rl & 63);
      int c = p ^ (rp & 7);                       // pre-swizzled SOURCE chunk
      aSrc[mh][i] = (co_base + rp) * 512 + c * 8;
      aDst[mh][i] = rp * 128 + p * 16;            // linear LDS dest
    }
  // B half f: striped rows {q*64 + f*32 + 0..31} (f=0 == b0-1 rows, f=1 == b2-3).
  int bSpa[2][2], bCc[2][2], bDst[2][2];
#pragma unroll
  for (int f = 0; f < 2; ++f)
#pragma unroll
    for (int i = 0; i < 2; ++i) {
      int d = i * 512 + tid;
      int rl = d >> 3, p = d & 7;
      int rp = ((rl >> 5) << 6) + f * 32 + (rl & 31);
      int c = p ^ (rp & 7);
      int m = pos_base + rp; if (m > HW - 1) m = HW - 1;   // tail clamp
      bSpa[f][i] = (m / 76) * 78 + (m - (m / 76) * 76);
      bCc[f][i] = c * 8;
      bDst[f][i] = 32768 + rp * 128 + p * 16;
    }

  // fragment read offsets (XOR chunk swizzle; row&7 == lm&7 for all fragments)
  const int koff0 = (lg ^ (lm & 7)) << 4;
  const int koff1 = ((4 + lg) ^ (lm & 7)) << 4;
  int aOff[8], bOff[4];
#pragma unroll
  for (int m = 0; m < 8; ++m) aOff[m] = (wm * 128 + m * 16 + lm) * 128;
#pragma unroll
  for (int n = 0; n < 4; ++n) bOff[n] = 32768 + (wn * 64 + n * 16 + lm) * 128;

  f32x4 acc[8][4];
#pragma unroll
  for (int i = 0; i < 8; ++i)
#pragma unroll
    for (int j = 0; j < 4; ++j) acc[i][j] = (f32x4){0.f, 0.f, 0.f, 0.f};

  bf16x8 ar[4][2], br[4][2];

#define STAGE_A(KT, BUF, MH) {                                                  \
    const int s_ = (KT) >> 3, cb_ = (KT) & 7;                                   \
    const bf16_t* p_ = Wt + (size_t)s_ * 262144 + cb_ * 64;                     \
    _Pragma("unroll")                                                           \
    for (int i_ = 0; i_ < 2; ++i_)                                              \
      gload_lds16(p_ + aSrc[MH][i_], (BUF) + aDst[MH][i_]);                     \
  }
#define STAGE_B(KT, BUF, F) {                                                   \
    const int s_ = (KT) >> 3, cb_ = (KT) & 7;                                   \
    const int sp_ = (s_ / 3) * 78 + (s_ - (s_ / 3) * 3);                        \
    _Pragma("unroll")                                                           \
    for (int i_ = 0; i_ < 2; ++i_)                                              \
      gload_lds16(XpB + (size_t)(bSpa[F][i_] + sp_) * 512 + bCc[F][i_] +        \
                      cb_ * 64,                                                 \
                  (BUF) + bDst[F][i_]);                                         \
  }
#define RD_A(BASE, MLO)                                                         \
    _Pragma("unroll")                                                           \
    for (int m_ = 0; m_ < 4; ++m_) {                                            \
      ar[m_][0] = *(const bf16x8*)((BASE) + aOff[(MLO) + m_] + koff0);          \
      ar[m_][1] = *(const bf16x8*)((BASE) + aOff[(MLO) + m_] + koff1);          \
    }
#define RD_B(BASE, NLO)                                                         \
    _Pragma("unroll")                                                           \
    for (int n_ = 0; n_ < 2; ++n_) {                                            \
      br[(NLO) + n_][0] = *(const bf16x8*)((BASE) + bOff[(NLO) + n_] + koff0);  \
      br[(NLO) + n_][1] = *(const bf16x8*)((BASE) + bOff[(NLO) + n_] + koff1);  \
    }
#define MF_Q(AM, NLO)                                                           \
    _Pragma("unroll")                                                           \
    for (int m_ = 0; m_ < 4; ++m_)                                              \
      _Pragma("unroll")                                                         \
      for (int n_ = 0; n_ < 2; ++n_)                                            \
        _Pragma("unroll")                                                       \
        for (int k_ = 0; k_ < 2; ++k_)                                          \
          acc[(AM) + m_][(NLO) + n_] = __builtin_amdgcn_mfma_f32_16x16x32_bf16( \
              ar[m_][k_], br[(NLO) + n_][k_], acc[(AM) + m_][(NLO) + n_], 0, 0, 0);
#define SYNC_MFMA                                                               \
    __builtin_amdgcn_s_barrier();                                               \
    asm volatile("s_waitcnt lgkmcnt(0)" ::: "memory");                          \
    __builtin_amdgcn_sched_barrier(0);
#define VM6 asm volatile("s_waitcnt vmcnt(6)" ::: "memory");
#define VM0 asm volatile("s_waitcnt vmcnt(0)" ::: "memory");
#define PRIO1 __builtin_amdgcn_s_setprio(1);
#define PRIO0 __builtin_amdgcn_s_setprio(0);
#define ENDP __builtin_amdgcn_s_barrier();

// One iteration = tiles (E, E+1); stages for E+2/E+3 enabled iff STG.
#define DO_ITER(E, STG, P4W, P8W) {                                             \
    char* bE = smem;                                                            \
    char* bO = smem + 65536;                                                    \
    /* P1 */ RD_B(bE, 0) RD_A(bE, 0) STAGE_A((E) + 1, bO, 1)                    \
      SYNC_MFMA PRIO1 MF_Q(0, 0) PRIO0 ENDP                                     \
    /* P2 */ RD_B(bE, 2) if (STG) STAGE_B((E) + 2, bE, 0)                       \
      SYNC_MFMA PRIO1 MF_Q(0, 2) PRIO0 ENDP                                     \
    /* P3 */ RD_A(bE, 4) if (STG) STAGE_A((E) + 2, bE, 0)                       \
      SYNC_MFMA PRIO1 MF_Q(4, 2) PRIO0 ENDP                                     \
    /* P4 */ if (STG) STAGE_B((E) + 2, bE, 1)                                   \
      SYNC_MFMA PRIO1 MF_Q(4, 0) PRIO0 P4W ENDP                                 \
    /* P5 */ RD_B(bO, 0) RD_A(bO, 0) if (STG) STAGE_A((E) + 2, bE, 1)           \
      SYNC_MFMA PRIO1 MF_Q(0, 0) PRIO0 ENDP                                     \
    /* P6 */ RD_B(bO, 2) if (STG) STAGE_B((E) + 3, bO, 0)                       \
      SYNC_MFMA PRIO1 MF_Q(0, 2) PRIO0 ENDP                                     \
    /* P7 */ RD_A(bO, 4) if (STG) STAGE_A((E) + 3, bO, 0)                       \
      SYNC_MFMA PRIO1 MF_Q(4, 2) PRIO0 ENDP                                     \
    /* P8 */ if (STG) STAGE_B((E) + 3, bO, 1)                                   \
      SYNC_MFMA PRIO1 MF_Q(4, 0) PRIO0 P8W ENDP                                 \
  }

  // prologue: tile0 {B0,A_lo,B1,A_hi} -> buf0; tile1 {B0,A_lo,B1} -> buf1
  STAGE_B(0, smem, 0) STAGE_A(0, smem, 0) STAGE_B(0, smem, 1) STAGE_A(0, smem, 1)
  STAGE_B(1, smem + 65536, 0) STAGE_A(1, smem + 65536, 0) STAGE_B(1, smem + 65536, 1)
  VM6                                    // drain tile0's 4 stages; tile1's 3 in flight
  __builtin_amdgcn_s_barrier();
  __builtin_amdgcn_sched_barrier(0);

  for (int it = 0; it < 35; ++it) {      // steady: tiles 0..69, all stages exist
    DO_ITER(2 * it, true, VM6, VM6)
  }
  DO_ITER(70, false, VM0, )              // tail: tiles 70,71; P1 stages A_hi(71)

#undef DO_ITER
#undef STAGE_A
#undef STAGE_B
#undef RD_A
#undef RD_B
#undef MF_Q
#undef SYNC_MFMA
#undef VM6
#undef VM0
#undef PRIO1
#undef PRIO0
#undef ENDP

  // epilogue: bias + ReLU, store NHWC rc2[(b*HW+pos)][co], 8B per fragment
  const size_t outRow = (size_t)b * HW;
#pragma unroll
  for (int m = 0; m < 8; ++m) {
    const int co = co_base + wm * 128 + m * 16 + lg * 4;
    const float4 bias = *(const float4*)(convb + co);
#pragma unroll
    for (int n = 0; n < 4; ++n) {
      const int pos = pos_base + wn * 64 + n * 16 + lm;
      if (pos < HW) {
        bf16x4 v;
        float z0 = acc[m][n][0] + bias.x; v[0] = (bf16_t)(z0 > 0.f ? z0 : 0.f);
        float z1 = acc[m][n][1] + bias.y; v[1] = (bf16_t)(z1 > 0.f ? z1 : 0.f);
        float z2 = acc[m][n][2] + bias.z; v[2] = (bf16_t)(z2 > 0.f ? z2 : 0.f);
        float z3 = acc[m][n][3] + bias.w; v[3] = (bf16_t)(z3 > 0.f ? z3 : 0.f);
        *(bf16x4*)(rc2 + (outRow + pos) * 512 + co) = v;
      }
    }
  }
}

// heads: C[64co][128pos] = Whb[64][512] x rc2[pos][512], fused bias/softmax/store.
__global__ __launch_bounds__(256) void heads_mfma(const bf16_t* __restrict__ rc2,
                                                  const bf16_t* __restrict__ Whb,
                                                  const float* __restrict__ clsb,
                                                  const float* __restrict__ boxb,
                                                  float* __restrict__ out) {
  __shared__ __align__(16) char smem[24576];  // A:[0,8K) B:[8K,24K)
  const int t = threadIdx.x, lane = t & 63, wv = t >> 6;
  const int lm = lane & 15, lg = lane >> 4, lx = lane & 7;
  const int pos_base = blockIdx.x * 128;

  int aSrc[2], bSrc[4];
#pragma unroll
  for (int i = 0; i < 2; ++i) {
    int d = i * 256 + t;
    int r = d >> 3, p = d & 7, c = p ^ (r & 7);
    aSrc[i] = r * 512 + c * 8;
  }
#pragma unroll
  for (int i = 0; i < 4; ++i) {
    int d = i * 256 + t;
    int r = d >> 3, p = d & 7, c = p ^ (r & 7);
    int pg = pos_base + r; if (pg > NPOS - 1) pg = NPOS - 1;
    bSrc[i] = pg * 512 + c * 8;
  }

  f32x4 acc[4][2];
#pragma unroll
  for (int i = 0; i < 4; ++i)
#pragma unroll
    for (int j = 0; j < 2; ++j) acc[i][j] = (f32x4){0.f, 0.f, 0.f, 0.f};

  for (int cb = 0; cb < 8; ++cb) {
    __syncthreads();
#pragma unroll
    for (int i = 0; i < 2; ++i) {
      int d = i * 256 + t;
      gload_lds16(Whb + aSrc[i] + cb * 64, &smem[d * 16]);
    }
#pragma unroll
    for (int i = 0; i < 4; ++i) {
      int d = i * 256 + t;
      gload_lds16(rc2 + (size_t)bSrc[i] + cb * 64, &smem[8192 + d * 16]);
    }
    __syncthreads();
#pragma unroll
    for (int ks = 0; ks < 2; ++ks) {
      const int koff = ((ks * 4 + lg) ^ lx) << 4;
      bf16x8 af[4], bfr[2];
#pragma unroll
      for (int f = 0; f < 4; ++f)
        af[f] = *(const bf16x8*)&smem[(f * 16 + lm) * 128 + koff];
#pragma unroll
      for (int f = 0; f < 2; ++f)
        bfr[f] = *(const bf16x8*)&smem[8192 + (wv * 32 + f * 16 + lm) * 128 + koff];
#pragma unroll
      for (int fa = 0; fa < 4; ++fa)
#pragma unroll
        for (int fb = 0; fb < 2; ++fb)
          acc[fa][fb] = __builtin_amdgcn_mfma_f32_16x16x32_bf16(
              af[fa], bfr[fb], acc[fa][fb], 0, 0, 0);
    }
  }

  float* boxOut = out + (size_t)8 * 18 * HW;
#pragma unroll
  for (int fb = 0; fb < 2; ++fb) {
    const int pg = pos_base + wv * 32 + fb * 16 + lm;
    if (pg < NPOS) {
      const int b = pg / HW;
      const int m = pg - b * HW;
#pragma unroll
      for (int fa = 0; fa < 4; ++fa) {
        const int base = fa * 16 + lg * 4;
#pragma unroll
        for (int pr = 0; pr < 2; ++pr) {
          const int row0 = base + pr * 2;
          const float v0 = acc[fa][fb][pr * 2];
          const float v1 = acc[fa][fb][pr * 2 + 1];
          if (row0 < 18) {
            const int a = row0 >> 1;
            const float s0 = v0 + clsb[a];
            const float s1 = v1 + clsb[9 + a];
            const float mx = fmaxf(s0, s1);
            const float e0 = expf(s0 - mx), e1 = expf(s1 - mx);
            const float inv = 1.0f / (e0 + e1);
            out[((size_t)(b * 18 + a)) * HW + m] = e0 * inv;
            out[((size_t)(b * 18 + 9 + a)) * HW + m] = e1 * inv;
          } else if (row0 < 54) {
            const int c0 = row0 - 18;
            boxOut[((size_t)(b * 36 + c0)) * HW + m] = v0 + boxb[c0];
            boxOut[((size_t)(b * 36 + c0 + 1)) * HW + m] = v1 + boxb[c0 + 1];
          }
        }
      }
    }
  }
}

extern "C" void kernel_launch(void* const* d_in, const int* in_sizes, int n_in,
                              void* d_out, int out_size, void* d_ws, size_t ws_size,
                              hipStream_t stream) {
  (void)in_sizes; (void)n_in; (void)out_size; (void)ws_size;
  const float* base_feat = (const float*)d_in[0];
  const float* conv_w = (const float*)d_in[4];
  const float* conv_b = (const float*)d_in[5];
  const float* cls_w  = (const float*)d_in[6];
  const float* cls_b  = (const float*)d_in[7];
  const float* bbox_w = (const float*)d_in[8];
  const float* bbox_b = (const float*)d_in[9];

  char* ws = (char*)d_ws;
  bf16_t* Xp  = (bf16_t*)(ws);                 // 8*52*78*512*2   = 33,226,752 B
  bf16_t* Wt  = (bf16_t*)(ws + 33226752);      // 9*512*512*2     =  4,718,592 B
  bf16_t* rc2 = (bf16_t*)(ws + 37945344);      // 30400*512*2     = 31,129,600 B (NHWC)
  bf16_t* Whb = (bf16_t*)(ws + 69074944);      // 64*512*2        =     65,536 B

  hipLaunchKernelGGL(pad_nhwc,   dim3(1616), dim3(256), 0, stream, base_feat, Xp);
  hipLaunchKernelGGL(wtrans,     dim3(512),  dim3(256), 0, stream, conv_w, Wt);
  hipLaunchKernelGGL(whb_build,  dim3(128),  dim3(256), 0, stream, cls_w, bbox_w, Whb);
  hipLaunchKernelGGL(conv3x3,    dim3(240),  dim3(512), 0, stream, Xp, Wt, conv_b, rc2);
  hipLaunchKernelGGL(heads_mfma, dim3(238),  dim3(256), 0, stream, rc2, Whb, cls_b, bbox_b,
                     (float*)d_out);
}